// Round 11
// baseline (443.505 us; speedup 1.0000x reference)
//
#include <hip/hip_runtime.h>
#include <hip/hip_bf16.h>
#include <math.h>

// Problem constants (N_WAY=64, K_SHOT=5, Q_QUERY=128, D_FEAT=128)
#define M     8192      // n*q query rows
#define D     128       // feature dim
#define NCLS  64        // n classes
#define KSHOT 5
#define XROW  133       // (k+q) rows per class in x
#define KTOP  9
#define KC    12        // candidate count (bf16x3 err ~3e-7 << gap(9,12) ~9e-3)
#define EPSV  1e-8f

// k2m: MFMA candidate pass. Block = 64 i (4 waves x 16-i subs) x 1024 j (SJ=8).
#define SJ    8
#define JPB   (M / SJ)      // 1024 j per block
#define NTIL  (JPB / 16)    // 64 j-tiles of 16
#define NPART (SJ * 2)      // 16 partial top-12 lists per i-row (lg-pairs merged)

typedef __attribute__((__ext_vector_type__(8))) short bf16v8;  // 8 bf16 = 4 VGPR
typedef __attribute__((__ext_vector_type__(4))) float f32v4;

// ---------------------------------------------------------------------------
// register-resident top-K with (value desc, index asc) tie-break, matching
// jax.lax.top_k set semantics. Fully unrolled -> static indexing -> VGPRs.
template <int KN>
__device__ __forceinline__ void topk_insert(float (&kv)[KN], int (&ki)[KN],
                                            float v, int j) {
  if (v > kv[KN - 1] || (v == kv[KN - 1] && j < ki[KN - 1])) {
    float cv = v; int cj = j;
#pragma unroll
    for (int t = 0; t < KN; ++t) {
      bool b = (cv > kv[t]) || (cv == kv[t] && cj < ki[t]);
      float tv = kv[t]; int ti_ = ki[t];
      kv[t] = b ? cv : tv;  ki[t] = b ? cj : ti_;
      cv   = b ? tv : cv;   cj   = b ? ti_ : cj;
    }
  }
}

// ---------------------------------------------------------------------------
__global__ void k0_proto(const float* __restrict__ x, float* __restrict__ protnT) {
  int c = blockIdx.x;
  int lane = threadIdx.x;
  const float* base = x + (size_t)(c * XROW) * D;
  float a0 = 0.f, a1 = 0.f;
#pragma unroll
  for (int s = 0; s < KSHOT; ++s) {
    a0 += base[s * D + lane];
    a1 += base[s * D + 64 + lane];
  }
  a0 *= 0.2f; a1 *= 0.2f;
  float ss = a0 * a0 + a1 * a1;
#pragma unroll
  for (int off = 1; off < 64; off <<= 1) ss += __shfl_xor(ss, off);
  float rn = 1.0f / fmaxf(sqrtf(ss), EPSV);
  protnT[lane * NCLS + c]        = a0 * rn;
  protnT[(lane + 64) * NCLS + c] = a1 * rn;
}

// ---------------------------------------------------------------------------
// k1: L2-normalize query rows -> qn (f32) and bf16 hi/lo split qh, ql.
__global__ void k1_qnorm(const float* __restrict__ x, float* __restrict__ qn,
                         short* __restrict__ qh, short* __restrict__ ql) {
  int lane = threadIdx.x & 63;
  int wv = threadIdx.x >> 6;
  int r = blockIdx.x * 4 + wv;
  int xr = (r >> 7) * XROW + KSHOT + (r & 127);
  const float* src = x + (size_t)xr * D;
  float v0 = src[lane], v1 = src[64 + lane];
  float ss = v0 * v0 + v1 * v1;
#pragma unroll
  for (int off = 1; off < 64; off <<= 1) ss += __shfl_xor(ss, off);
  float rn = 1.0f / fmaxf(sqrtf(ss), EPSV);
  float q0 = v0 * rn, q1 = v1 * rn;
  qn[(size_t)r * D + lane]      = q0;
  qn[(size_t)r * D + 64 + lane] = q1;
  __hip_bfloat16 h0 = __float2bfloat16(q0);
  __hip_bfloat16 h1 = __float2bfloat16(q1);
  __hip_bfloat16 l0 = __float2bfloat16(q0 - __bfloat162float(h0));
  __hip_bfloat16 l1 = __float2bfloat16(q1 - __bfloat162float(h1));
  qh[(size_t)r * D + lane]      = *(short*)&h0;
  qh[(size_t)r * D + 64 + lane] = *(short*)&h1;
  ql[(size_t)r * D + lane]      = *(short*)&l0;
  ql[(size_t)r * D + 64 + lane] = *(short*)&l1;
}

// ---------------------------------------------------------------------------
// k2m v2: bf16x3 MFMA candidate generation, stall-minimized.
//  - 3 independent acc chains (hh, hl, lh) -> MFMA dep depth 4, not 12
//  - double-buffered 16-j tile, ONE barrier per tile
//  - per-tile max4 gate before any insert body
//  - no LDS merge: lg-pair register shuffle merge, NPART=16 global lists
// D layout (m89-verified): i-col = lane&15, j-row = (lane>>4)*4 + reg.
__global__ __launch_bounds__(256) void
k2m(const short* __restrict__ qh, const short* __restrict__ ql,
    float* __restrict__ pkv, int* __restrict__ pki) {
  __shared__ __align__(16) short jh[2][16 * D];   // 2 x 4 KB j-tile hi
  __shared__ __align__(16) short jl[2][16 * D];   // 2 x 4 KB j-tile lo

  const int tid  = threadIdx.x;
  const int l    = tid & 63;
  const int w    = tid >> 6;
  const int ib   = blockIdx.x >> 3;        // 128 i-strips of 64
  const int js   = blockIdx.x & (SJ - 1);  // 8 j-splits
  const int i0   = ib * 64;
  const int j0s  = js * JPB;

  const bf16v8* qh8 = (const bf16v8*)qh;
  const bf16v8* ql8 = (const bf16v8*)ql;

  // ---- persistent i-side B fragments: lane's i-row, 4 k-windows ----
  const int irow = i0 + w * 16 + (l & 15);
  const int lg   = l >> 4;                 // k-group 0..3
  bf16v8 bh[4], bl[4];
#pragma unroll
  for (int kk = 0; kk < 4; ++kk) {
    bh[kk] = qh8[(size_t)irow * 16 + kk * 4 + lg];
    bl[kk] = ql8[(size_t)irow * 16 + kk * 4 + lg];
  }

  float kv[KC]; int ki[KC];
#pragma unroll
  for (int t = 0; t < KC; ++t) { kv[t] = -INFINITY; ki[t] = 0x7fffffff; }

  // stage indexing: thread t -> (row, chunk); XOR-swizzle chunk by row&7
  const int srow = tid >> 4;               // 0..15
  const int schk = tid & 15;               // 0..15
  const int sslot = srow * 16 + (schk ^ (srow & 7));
  const int arow = l & 15;                 // A-frag j-row within tile

  // swizzled read slots (loop-invariant)
  int rslot[4];
#pragma unroll
  for (int kk = 0; kk < 4; ++kk)
    rslot[kk] = arow * 16 + ((kk * 4 + lg) ^ (arow & 7));

  // ---- prologue: tile 0 -> buf0; prefetch tile 1 to regs ----
  bf16v8 sa = qh8[(size_t)(j0s + srow) * 16 + schk];
  bf16v8 sb = ql8[(size_t)(j0s + srow) * 16 + schk];
  ((bf16v8*)jh[0])[sslot] = sa;
  ((bf16v8*)jl[0])[sslot] = sb;
  sa = qh8[(size_t)(j0s + 16 + srow) * 16 + schk];
  sb = ql8[(size_t)(j0s + 16 + srow) * 16 + schk];
  __syncthreads();

  for (int t = 0; t < NTIL; ++t) {
    // write next tile into the other buffer (its readers finished at the
    // barrier ending iteration t-1), then prefetch t+2 from global
    if (t + 1 < NTIL) {
      ((bf16v8*)jh[(t + 1) & 1])[sslot] = sa;
      ((bf16v8*)jl[(t + 1) & 1])[sslot] = sb;
      if (t + 2 < NTIL) {
        sa = qh8[(size_t)(j0s + (t + 2) * 16 + srow) * 16 + schk];
        sb = ql8[(size_t)(j0s + (t + 2) * 16 + srow) * 16 + schk];
      }
    }

    const bf16v8* H = (const bf16v8*)jh[t & 1];
    const bf16v8* L = (const bf16v8*)jl[t & 1];
    f32v4 a0 = {0.f, 0.f, 0.f, 0.f};
    f32v4 a1 = {0.f, 0.f, 0.f, 0.f};
    f32v4 a2 = {0.f, 0.f, 0.f, 0.f};
#pragma unroll
    for (int kk = 0; kk < 4; ++kk) {
      bf16v8 ah = H[rslot[kk]];
      bf16v8 al = L[rslot[kk]];
      a0 = __builtin_amdgcn_mfma_f32_16x16x32_bf16(ah, bh[kk], a0, 0, 0, 0);
      a1 = __builtin_amdgcn_mfma_f32_16x16x32_bf16(ah, bl[kk], a1, 0, 0, 0);
      a2 = __builtin_amdgcn_mfma_f32_16x16x32_bf16(al, bh[kk], a2, 0, 0, 0);
    }
    f32v4 s = a0 + a1 + a2;

    const int jb = j0s + t * 16 + lg * 4;  // lane's 4 j-rows
    float vmax = fmaxf(fmaxf(s[0], s[1]), fmaxf(s[2], s[3]));
    if (vmax > kv[KC - 1] || (vmax == kv[KC - 1] && jb < ki[KC - 1])) {
      topk_insert<KC>(kv, ki, s[0], jb + 0);
      topk_insert<KC>(kv, ki, s[1], jb + 1);
      topk_insert<KC>(kv, ki, s[2], jb + 2);
      topk_insert<KC>(kv, ki, s[3], jb + 3);
    }

    __syncthreads();   // readers of buf[t&1] done; writes to buf[(t+1)&1] visible
  }

  // ---- lg-pair register merge: lanes lg^1 exchange lists, even-lg keeps ----
#pragma unroll
  for (int t = 0; t < KC; ++t) {
    float pv = __shfl(kv[t], l ^ 16);
    int   pj = __shfl(ki[t], l ^ 16);
    if ((l & 16) == 0) topk_insert<KC>(kv, ki, pv, pj);
  }

  if ((l & 16) == 0) {                     // lg in {0,2}: write partial list
    int i = i0 + w * 16 + (l & 15);
    int p = js * 2 + (l >> 5);
    size_t base = ((size_t)i * NPART + p) * KC;
#pragma unroll
    for (int t = 0; t < KC; ++t) { pkv[base + t] = kv[t]; pki[base + t] = ki[t]; }
  }
}

// ---------------------------------------------------------------------------
// k_merge: per row, merge 16 partial top-12 lists -> 12 candidate indices.
__global__ void k_merge(const float* __restrict__ pkv, const int* __restrict__ pki,
                        int* __restrict__ cand) {
  int i = blockIdx.x * blockDim.x + threadIdx.x;
  float kv[KC]; int ki[KC];
#pragma unroll
  for (int t = 0; t < KC; ++t) { kv[t] = -INFINITY; ki[t] = 0x7fffffff; }
  const float* pv = pkv + (size_t)i * NPART * KC;
  const int*   pi = pki + (size_t)i * NPART * KC;
  for (int t = 0; t < NPART * KC; ++t) topk_insert<KC>(kv, ki, pv[t], pi[t]);
#pragma unroll
  for (int t = 0; t < KC; ++t) cand[(size_t)i * KC + t] = ki[t];
}

// ---------------------------------------------------------------------------
// k_rerank: exact fp32 dots for the 12 candidates; exact top-9 (jax tie-break).
// This firewall makes the bf16x3 candidate pass precision-irrelevant.
__global__ void k_rerank(const float* __restrict__ qn, const int* __restrict__ cand,
                         float* __restrict__ kval, int* __restrict__ kidx) {
  int lane = threadIdx.x & 63;
  int wv   = threadIdx.x >> 6;
  int i = blockIdx.x * 4 + wv;
  int jc = cand[(size_t)i * KC + (lane < KC ? lane : KC - 1)];
  const float4* qi = (const float4*)(qn + (size_t)i * D);
  const float4* qj = (const float4*)(qn + (size_t)jc * D);
  float dot = 0.f;
#pragma unroll
  for (int c = 0; c < 32; ++c) {
    float4 a = qi[c], b = qj[c];
    dot += a.x * b.x + a.y * b.y + a.z * b.z + a.w * b.w;
  }
  float kv[KTOP]; int ki[KTOP];
#pragma unroll
  for (int t = 0; t < KTOP; ++t) { kv[t] = -INFINITY; ki[t] = 0x7fffffff; }
#pragma unroll
  for (int t = 0; t < KC; ++t) {
    float v = __shfl(dot, t);
    int   jv = __shfl(jc, t);
    topk_insert<KTOP>(kv, ki, v, jv);
  }
  if (lane == 0) {
#pragma unroll
    for (int t = 0; t < KTOP; ++t) {
      kval[(size_t)i * KTOP + t] = kv[t];
      kidx[(size_t)i * KTOP + t] = ki[t];
    }
  }
}

// ---------------------------------------------------------------------------
// k3: mutual mask + softmax over <=9 entries + adapted query + normalize +
// project on normalized prototypes, scale by tao. One wave per query row.
__global__ void k3_out(const float* __restrict__ x, const float* __restrict__ kval,
                       const int* __restrict__ kidx, const float* __restrict__ protnT,
                       const float* __restrict__ taop, float* __restrict__ out) {
  __shared__ float sw[4][KTOP];
  __shared__ int   sj[4][KTOP];
  __shared__ float an[4][D];
  int lane = threadIdx.x & 63;
  int wv   = threadIdx.x >> 6;
  int i = blockIdx.x * 4 + wv;

  float v = -INFINITY; int jt = 0; bool mut = false;
  if (lane < KTOP) {
    v  = kval[(size_t)i * KTOP + lane];
    jt = kidx[(size_t)i * KTOP + lane];
    const int* oj = kidx + (size_t)jt * KTOP;
#pragma unroll
    for (int t = 0; t < KTOP; ++t) mut = mut || (oj[t] == i);
  }
  float lv = mut ? v : -INFINITY;
#pragma unroll
  for (int off = 1; off < 16; off <<= 1) lv = fmaxf(lv, __shfl_xor(lv, off));
  float wexp = mut ? expf(v - lv) : 0.f;    // self is always mutual -> z >= 1
  float z = wexp;
#pragma unroll
  for (int off = 1; off < 16; off <<= 1) z += __shfl_xor(z, off);
  if (lane < KTOP) { sw[wv][lane] = wexp / z; sj[wv][lane] = jt; }
  __syncthreads();

  float a0 = 0.f, a1 = 0.f;
#pragma unroll
  for (int t = 0; t < KTOP; ++t) {
    float wt = sw[wv][t];
    if (wt != 0.f) {
      int j = sj[wv][t];
      int xr = (j >> 7) * XROW + KSHOT + (j & 127);
      const float* qr = x + (size_t)xr * D;
      a0 += wt * qr[lane];
      a1 += wt * qr[64 + lane];
    }
  }
  float ss = a0 * a0 + a1 * a1;
#pragma unroll
  for (int off = 1; off < 64; off <<= 1) ss += __shfl_xor(ss, off);
  float rn = 1.0f / fmaxf(sqrtf(ss), EPSV);
  an[wv][lane]      = a0 * rn;
  an[wv][64 + lane] = a1 * rn;
  __syncthreads();

  float acc = 0.f;
#pragma unroll 8
  for (int d = 0; d < D; ++d) acc += an[wv][d] * protnT[d * NCLS + lane];
  out[(size_t)i * NCLS + lane] = taop[0] * acc;
}

// ---------------------------------------------------------------------------
extern "C" void kernel_launch(void* const* d_in, const int* in_sizes, int n_in,
                              void* d_out, int out_size, void* d_ws, size_t ws_size,
                              hipStream_t stream) {
  const float* x   = (const float*)d_in[0];
  const float* tao = (const float*)d_in[1];
  float* out = (float*)d_out;

  // workspace layout, ~21 MB total
  float* qn   = (float*)d_ws;                         // 8192*128 f32 (4 MB)
  short* qh   = (short*)(qn + (size_t)M * D);         // 2 MB bf16 hi
  short* ql   = qh + (size_t)M * D;                   // 2 MB bf16 lo
  float* pkv  = (float*)(ql + (size_t)M * D);         // 8192*16*12 (6.3 MB)
  int*   pki  = (int*)(pkv + (size_t)M * NPART * KC); // 6.3 MB
  int*   cand = pki + (size_t)M * NPART * KC;         // 8192*12 (0.4 MB)
  float* kval = (float*)(cand + (size_t)M * KC);      // 8192*9
  int*   kidx = (int*)(kval + (size_t)M * KTOP);
  float* protnT = (float*)(kidx + (size_t)M * KTOP);  // 128*64

  k0_proto<<<NCLS, 64, 0, stream>>>(x, protnT);
  k1_qnorm<<<M / 4, 256, 0, stream>>>(x, qn, qh, ql);
  k2m<<<(M / 64) * SJ, 256, 0, stream>>>(qh, ql, pkv, pki);
  k_merge<<<M / 256, 256, 0, stream>>>(pkv, pki, cand);
  k_rerank<<<M / 4, 256, 0, stream>>>(qn, cand, kval, kidx);
  k3_out<<<M / 4, 256, 0, stream>>>(x, kval, kidx, protnT, tao, out);
}